// Round 8
// baseline (395.076 us; speedup 1.0000x reference)
//
#include <hip/hip_runtime.h>
#include <hip/hip_bf16.h>

using uint32 = unsigned int;
using u16 = unsigned short;
using short8 = __attribute__((ext_vector_type(8))) short;
using f32x4  = __attribute__((ext_vector_type(4))) float;

// ---------- bf16 helpers ----------
__device__ __forceinline__ float bf2f(u16 u) {
  union { uint32 i; float f; } c; c.i = ((uint32)u) << 16; return c.f;
}
__device__ __forceinline__ u16 f2bf(float f) {
  union { float f; uint32 i; } c; c.f = f;
  uint32 u = c.i;
  u += 0x7fffu + ((u >> 16) & 1u);   // RNE
  return (u16)(u >> 16);
}
__device__ __forceinline__ uint32 pack2(float a, float b) {
  return (uint32)f2bf(a) | ((uint32)f2bf(b) << 16);
}

// async global->LDS, 16B per lane. LDS dest: wave-uniform base (+lane*16 by HW);
// global src: per-lane address.
__device__ __forceinline__ void gload_lds16(const void* g, void* l) {
  __builtin_amdgcn_global_load_lds(
      (const __attribute__((address_space(1))) unsigned int*)g,
      (__attribute__((address_space(3))) unsigned int*)l, 16, 0, 0);
}

// Sizes: B=16, C=64, W=256, H=128, H'=122, KW=7
// k/q layout: [b][co][w][h'] contiguous == (B,256,7808) attention rows
// raw flatten: row j=(c=j>>2, wblk=j&3); col e=(dw=e>>7, h=e&127)
// x/z tiles: per (b,w) [128 h][64 ci^((h&7)<<3)] bf16, 16384B

// ---------------------------------------------------------------
// Kernel 0: prep weights -> bf16 [kw][co][ci]
// ---------------------------------------------------------------
__global__ __launch_bounds__(256) void prep_weights(
    const float* __restrict__ wK, const float* __restrict__ wQ,
    const float* __restrict__ wV,
    u16* __restrict__ pK, u16* __restrict__ pQ, u16* __restrict__ pV)
{
  int idx = blockIdx.x * 256 + threadIdx.x;   // 0..86015
  if (idx >= 86016) return;
  int set = idx / 28672;
  int r = idx - set * 28672;                  // kw*4096 + co*64 + ci
  int kw = r >> 12;
  int rem = r & 4095;
  int co = rem >> 6, ci = rem & 63;
  const float* src = set == 0 ? wK : (set == 1 ? wQ : wV);
  u16* dst = set == 0 ? pK : (set == 1 ? pQ : pV);
  dst[r] = f2bf(src[co * 448 + ci * 7 + kw]);
}

// ---------------------------------------------------------------
// Kernel 0b: x -> swizzled bf16 tiles (streaming, full occupancy)
// ---------------------------------------------------------------
__global__ __launch_bounds__(256) void prep_x(
    const float* __restrict__ x, u16* __restrict__ xbuf)
{
  __shared__ u16 xt[128 * 64];
  const int bid = blockIdx.x;         // b*256 + w
  const int b = bid >> 8, w = bid & 255;
  const int t = threadIdx.x;
  const float* xb = x + (size_t)b * 2097152 + (size_t)w * 128;
  #pragma unroll
  for (int it = 0; it < 8; ++it) {
    int idx = t + it * 256;
    int h = idx & 127, gq = idx >> 7;
    int ci0 = gq * 4;
    float v0 = xb[(size_t)(ci0 + 0) * 32768 + h];
    float v1 = xb[(size_t)(ci0 + 1) * 32768 + h];
    float v2 = xb[(size_t)(ci0 + 2) * 32768 + h];
    float v3 = xb[(size_t)(ci0 + 3) * 32768 + h];
    uint2 pk; pk.x = pack2(v0, v1); pk.y = pack2(v2, v3);
    int col = ci0 ^ ((h & 7) << 3);
    *reinterpret_cast<uint2*>(&xt[h * 64 + col]) = pk;
  }
  __syncthreads();
  const uint4* s = reinterpret_cast<const uint4*>(xt);
  uint4* d = reinterpret_cast<uint4*>(xbuf + (size_t)bid * 8192);
  #pragma unroll
  for (int it = 0; it < 4; ++it) d[t + it * 256] = s[t + it * 256];
}

// ---------------------------------------------------------------
// Kernel 0c: raw z (bf16) -> swizzled z tiles (streaming)
// ---------------------------------------------------------------
__global__ __launch_bounds__(256) void prep_z(
    const u16* __restrict__ zraw, u16* __restrict__ ztbuf)
{
  __shared__ u16 xt[128 * 64];
  const int bid = blockIdx.x;         // b*256 + w
  const int b = bid >> 8, w = bid & 255;
  const int t = threadIdx.x;
  const u16* zb = zraw + (size_t)b * 2097152 + (size_t)w * 128;
  #pragma unroll
  for (int it = 0; it < 8; ++it) {
    int idx = t + it * 256;
    int h = idx & 127, gq = idx >> 7;
    int ci0 = gq * 4;
    u16 v0 = zb[(size_t)(ci0 + 0) * 32768 + h];
    u16 v1 = zb[(size_t)(ci0 + 1) * 32768 + h];
    u16 v2 = zb[(size_t)(ci0 + 2) * 32768 + h];
    u16 v3 = zb[(size_t)(ci0 + 3) * 32768 + h];
    uint2 pk;
    pk.x = (uint32)v0 | ((uint32)v1 << 16);
    pk.y = (uint32)v2 | ((uint32)v3 << 16);
    int col = ci0 ^ ((h & 7) << 3);
    *reinterpret_cast<uint2*>(&xt[h * 64 + col]) = pk;
  }
  __syncthreads();
  const uint4* s = reinterpret_cast<const uint4*>(xt);
  uint4* d = reinterpret_cast<uint4*>(ztbuf + (size_t)bid * 8192);
  #pragma unroll
  for (int it = 0; it < 4; ++it) d[t + it * 256] = s[t + it * 256];
}

// ---------------------------------------------------------------
// Kernel 1: K and Q convs via MFMA. Staging = global_load_lds of the
// pre-swizzled tile (fire-and-forget). K-loop = pure LDS + MFMA
// (weights direct from L2-resident global).
// ---------------------------------------------------------------
__global__ __launch_bounds__(256, 4) void conv_kq_mfma(
    const u16* __restrict__ xbuf,
    const u16* __restrict__ wpK, const u16* __restrict__ wpQ,
    const float* __restrict__ bK, const float* __restrict__ bQ,
    u16* __restrict__ qbuf, u16* __restrict__ kbuf)
{
  __shared__ u16 xt[136 * 64];
  const int bid = blockIdx.x;
  const int b = bid >> 8, w = bid & 255;
  const int t = threadIdx.x;
  const int lane = t & 63, wv = t >> 6;
  const int ln = lane & 15, g = lane >> 4;

  {
    const u16* src = xbuf + (size_t)bid * 8192;
    #pragma unroll
    for (int c = 0; c < 4; ++c) {
      int chunk = wv * 4 + c;                       // 16 chunks x 1024B
      gload_lds16(src + chunk * 512 + lane * 8, &xt[chunk * 512]);
    }
    if (t < 128) {   // zero pad rows 128..135
      *reinterpret_cast<uint2*>(&xt[128 * 64 + t * 4]) = make_uint2(0u, 0u);
    }
  }
  asm volatile("s_waitcnt vmcnt(0)" ::: "memory");
  __syncthreads();

  f32x4 accK[8], accQ[8];
  #pragma unroll
  for (int j = 0; j < 8; ++j) { accK[j] = (f32x4)0.f; accQ[j] = (f32x4)0.f; }

  for (int kw = 0; kw < 7; ++kw) {
    #pragma unroll
    for (int ks = 0; ks < 2; ++ks) {
      const int kb = ks * 32 + g * 8;
      const size_t woff = (size_t)(kw * 64 + wv * 16 + ln) * 64 + kb;
      short8 aK = *reinterpret_cast<const short8*>(wpK + woff);
      short8 aQ = *reinterpret_cast<const short8*>(wpQ + woff);
      #pragma unroll
      for (int j = 0; j < 8; ++j) {
        int row = j * 16 + ln + kw;
        int col = kb ^ ((row & 7) << 3);
        short8 bf = *reinterpret_cast<const short8*>(&xt[row * 64 + col]);
        accK[j] = __builtin_amdgcn_mfma_f32_16x16x32_bf16(aK, bf, accK[j], 0, 0, 0);
        accQ[j] = __builtin_amdgcn_mfma_f32_16x16x32_bf16(aQ, bf, accQ[j], 0, 0, 0);
      }
    }
  }

  #pragma unroll
  for (int r = 0; r < 4; ++r) {
    int co = wv * 16 + g * 4 + r;
    float bk = bK[co], bq = bQ[co];
    size_t base = ((size_t)(b * 64 + co) * 256 + w) * 122;
    #pragma unroll
    for (int j = 0; j < 8; ++j) {
      int n = j * 16 + ln;
      if (n < 122) {
        kbuf[base + n] = f2bf(accK[j][r] + bk);
        qbuf[base + n] = f2bf(accQ[j][r] + bq);
      }
    }
  }
}

// ---------------------------------------------------------------
// Kernel 2a: scores via MFMA + fused masked softmax -> pbuf bf16
// ---------------------------------------------------------------
__global__ __launch_bounds__(256) void scores_mfma(
    const u16* __restrict__ qbuf, const u16* __restrict__ kbuf,
    u16* __restrict__ pbuf)
{
  __shared__ float lmax[4][16];
  __shared__ float lsum[4][16];
  const int bid = blockIdx.x;
  const int b = bid & 15, rt = bid >> 4;
  const int t = threadIdx.x;
  const int lane = t & 63, wq = t >> 6;
  const int g = lane >> 4, ln = lane & 15;
  const int i0 = rt * 16;
  const int jbase = (rt < 8) ? 128 : 0;

  const u16* qp  = qbuf + (size_t)(b * 256 + i0 + ln) * 7808 + g * 8;
  const u16* kp0 = kbuf + (size_t)(b * 256 + jbase + wq * 32 + ln) * 7808 + g * 8;
  const u16* kp1 = kp0 + (size_t)16 * 7808;

  f32x4 acc0 = (f32x4)0.f, acc1 = (f32x4)0.f;
  #pragma unroll 4
  for (int c = 0; c < 244; ++c) {
    short8 af = *reinterpret_cast<const short8*>(qp + c * 32);
    short8 b0 = *reinterpret_cast<const short8*>(kp0 + c * 32);
    short8 b1 = *reinterpret_cast<const short8*>(kp1 + c * 32);
    acc0 = __builtin_amdgcn_mfma_f32_16x16x32_bf16(af, b0, acc0, 0, 0, 0);
    acc1 = __builtin_amdgcn_mfma_f32_16x16x32_bf16(af, b1, acc1, 0, 0, 0);
  }

  const float scale = 0.011316967f;    // 1/sqrt(7808)
  float s0[4], s1[4];
  #pragma unroll
  for (int r = 0; r < 4; ++r) { s0[r] = acc0[r] * scale; s1[r] = acc1[r] * scale; }

  float pm[4], ps[4];
  #pragma unroll
  for (int r = 0; r < 4; ++r) {
    float m = fmaxf(s0[r], s1[r]);
    #pragma unroll
    for (int off = 8; off >= 1; off >>= 1) m = fmaxf(m, __shfl_xor(m, off));
    float e = __expf(s0[r] - m) + __expf(s1[r] - m);
    #pragma unroll
    for (int off = 8; off >= 1; off >>= 1) e += __shfl_xor(e, off);
    pm[r] = m; ps[r] = e;
  }
  if (ln == 0) {
    #pragma unroll
    for (int r = 0; r < 4; ++r) {
      lmax[wq][g * 4 + r] = pm[r];
      lsum[wq][g * 4 + r] = ps[r];
    }
  }
  __syncthreads();

  #pragma unroll
  for (int r = 0; r < 4; ++r) {
    int row = g * 4 + r;
    float m0 = lmax[0][row], m1 = lmax[1][row], m2 = lmax[2][row], m3 = lmax[3][row];
    float mm = fmaxf(fmaxf(m0, m1), fmaxf(m2, m3));
    float ss = lsum[0][row] * __expf(m0 - mm) + lsum[1][row] * __expf(m1 - mm)
             + lsum[2][row] * __expf(m2 - mm) + lsum[3][row] * __expf(m3 - mm);
    float inv = 1.0f / ss;
    float p0 = __expf(s0[r] - mm) * inv;
    float p1 = __expf(s1[r] - mm) * inv;
    u16* prow = pbuf + (size_t)(b * 256 + i0 + row) * 128 + wq * 32 + ln;
    prow[0]  = f2bf(p0);
    prow[16] = f2bf(p1);
  }
}

// ---------------------------------------------------------------
// Kernel 2b: z = x + P*V via MFMA, bf16 out (raw layout) — proven R4-R6
// structure; P staged from bf16 pbuf (straight copy).
// ---------------------------------------------------------------
__global__ __launch_bounds__(256) void pv_mfma(
    const u16* __restrict__ pbuf, const float* __restrict__ x,
    u16* __restrict__ zraw)
{
  __shared__ u16 pl[128 * 136];   // 34816 B
  __shared__ u16 vt[256 * 40];    // 20480 B
  const int bid = blockIdx.x;
  const int b  = bid >> 6;
  const int hb = (bid >> 5) & 1;
  const int ec = bid & 31;
  const int t = threadIdx.x;
  const int lane = t & 63, wv = t >> 6;
  const int ln = lane & 15, g = lane >> 4;

  const int i0 = hb ? 0 : 128;        // output rows
  const int jbase = hb ? 128 : 0;     // V rows (opposite half)
  const int e0 = ec * 256;
  const float* xb = x + (size_t)b * 2097152;

  // stage P (bf16 rows, pad stride 136)
  {
    const u16* pb = pbuf + (size_t)(b * 256 + i0) * 128;
    #pragma unroll
    for (int it = 0; it < 8; ++it) {
      int idx = t + it * 256;           // 0..2047 uint4
      int row = idx >> 4, c = idx & 15;
      uint4 v = *reinterpret_cast<const uint4*>(pb + row * 128 + c * 8);
      *reinterpret_cast<uint4*>(&pl[row * 136 + c * 8]) = v;
    }
  }

  f32x4 acc[2][16];
  #pragma unroll
  for (int mt = 0; mt < 2; ++mt)
    #pragma unroll
    for (int nt = 0; nt < 16; ++nt) acc[mt][nt] = (f32x4)0.f;

  uint32* vtw = reinterpret_cast<uint32*>(vt);
  for (int ks = 0; ks < 4; ++ks) {
    __syncthreads();
    // stage V^T k-step: raw V rows jbase+ks*32..+32, cols e0..e0+256
    #pragma unroll
    for (int it = 0; it < 16; ++it) {
      int idx = t + it * 256;           // 0..4095
      int e = idx & 255, jp = idx >> 8;
      const float* vr = xb + (size_t)(jbase + ks * 32 + jp * 2) * 8192 + e0 + e;
      float f0 = vr[0];
      float f1 = vr[8192];
      vtw[e * 20 + jp] = pack2(f0, f1);
    }
    __syncthreads();
    short8 af[2];
    #pragma unroll
    for (int mt = 0; mt < 2; ++mt) {
      int row = wv * 32 + mt * 16 + ln;
      af[mt] = *reinterpret_cast<const short8*>(&pl[row * 136 + ks * 32 + g * 8]);
    }
    #pragma unroll
    for (int nt = 0; nt < 16; ++nt) {
      int e = nt * 16 + ln;
      short8 bf = *reinterpret_cast<const short8*>(&vt[e * 40 + g * 8]);
      acc[0][nt] = __builtin_amdgcn_mfma_f32_16x16x32_bf16(af[0], bf, acc[0][nt], 0, 0, 0);
      acc[1][nt] = __builtin_amdgcn_mfma_f32_16x16x32_bf16(af[1], bf, acc[1][nt], 0, 0, 0);
    }
  }

  // epilogue: z = x + acc -> bf16 raw (D: col = ln -> e, row = g*4+r)
  #pragma unroll
  for (int mt = 0; mt < 2; ++mt) {
    #pragma unroll
    for (int r = 0; r < 4; ++r) {
      int i = i0 + wv * 32 + mt * 16 + g * 4 + r;
      const float* xr = xb + (size_t)i * 8192 + e0 + ln;
      u16* zr = zraw + (size_t)(b * 256 + i) * 8192 + e0 + ln;
      #pragma unroll
      for (int nt = 0; nt < 16; ++nt) {
        float z = xr[nt * 16] + acc[mt][nt][r];
        zr[nt * 16] = f2bf(z);
      }
    }
  }
}

// ---------------------------------------------------------------
// Kernel 3: y = LeakyReLU(conv(z, wV) + bV) via MFMA, fp32 out.
// Staging via global_load_lds from z tiles.
// ---------------------------------------------------------------
__global__ __launch_bounds__(256, 4) void conv_out_mfma(
    const u16* __restrict__ ztbuf, const u16* __restrict__ wpV,
    const float* __restrict__ bV, float* __restrict__ out)
{
  __shared__ u16 xt[136 * 64];
  const int bid = blockIdx.x;
  const int b = bid >> 8, w = bid & 255;
  const int t = threadIdx.x;
  const int lane = t & 63, wv = t >> 6;
  const int ln = lane & 15, g = lane >> 4;

  {
    const u16* src = ztbuf + (size_t)bid * 8192;
    #pragma unroll
    for (int c = 0; c < 4; ++c) {
      int chunk = wv * 4 + c;
      gload_lds16(src + chunk * 512 + lane * 8, &xt[chunk * 512]);
    }
    if (t < 128) {
      *reinterpret_cast<uint2*>(&xt[128 * 64 + t * 4]) = make_uint2(0u, 0u);
    }
  }
  asm volatile("s_waitcnt vmcnt(0)" ::: "memory");
  __syncthreads();

  f32x4 acc[8];
  #pragma unroll
  for (int j = 0; j < 8; ++j) acc[j] = (f32x4)0.f;

  for (int kw = 0; kw < 7; ++kw) {
    #pragma unroll
    for (int ks = 0; ks < 2; ++ks) {
      const int kb = ks * 32 + g * 8;
      const size_t woff = (size_t)(kw * 64 + wv * 16 + ln) * 64 + kb;
      short8 aV = *reinterpret_cast<const short8*>(wpV + woff);
      #pragma unroll
      for (int j = 0; j < 8; ++j) {
        int row = j * 16 + ln + kw;
        int col = kb ^ ((row & 7) << 3);
        short8 bf = *reinterpret_cast<const short8*>(&xt[row * 64 + col]);
        acc[j] = __builtin_amdgcn_mfma_f32_16x16x32_bf16(aV, bf, acc[j], 0, 0, 0);
      }
    }
  }

  #pragma unroll
  for (int r = 0; r < 4; ++r) {
    int co = wv * 16 + g * 4 + r;
    float bv = bV[co];
    size_t base = ((size_t)(b * 64 + co) * 256 + w) * 122;
    #pragma unroll
    for (int j = 0; j < 8; ++j) {
      int n = j * 16 + ln;
      if (n < 122) {
        float y = acc[j][r] + bv;
        out[base + n] = (y >= 0.f) ? y : 0.2f * y;
      }
    }
  }
}

// ---------------------------------------------------------------
extern "C" void kernel_launch(void* const* d_in, const int* in_sizes, int n_in,
                              void* d_out, int out_size, void* d_ws, size_t ws_size,
                              hipStream_t stream) {
  const float* x  = (const float*)d_in[0];
  const float* wK = (const float*)d_in[1];
  const float* bK = (const float*)d_in[2];
  const float* wQ = (const float*)d_in[3];
  const float* bQ = (const float*)d_in[4];
  const float* wV = (const float*)d_in[5];
  const float* bV = (const float*)d_in[6];
  float* out = (float*)d_out;

  // workspace layout (196,255,744 B total):
  // [0)            qbuf bf16        63,963,136   dead after scores
  // [63,963,136)   pbuf bf16         1,048,576   dead after pv
  // [65,011,712)   wpK bf16             57,344   dead after conv_kq
  // [65,069,056)   wpQ bf16             57,344   dead after conv_kq
  // [65,126,400)   kbuf bf16        63,963,136   dead after scores
  // [129,089,536)  X: xbuf->zraw    67,108,864   (xbuf dead after conv_kq)
  // [196,198,400)  wpV bf16             57,344   live to conv_out
  // ztbuf @ 0 (67,108,864) overlays qbuf/pbuf/wpK/wpQ/kbuf-head — all dead
  // by the time prep_z writes it.
  char* ws = (char*)d_ws;
  u16* qbuf  = (u16*)ws;
  u16* pbuf  = (u16*)(ws + 63963136);
  u16* wpK   = (u16*)(ws + 65011712);
  u16* wpQ   = (u16*)(ws + 65069056);
  u16* kbuf  = (u16*)(ws + 65126400);
  u16* xbuf  = (u16*)(ws + 129089536);
  u16* zraw  = xbuf;
  u16* wpV   = (u16*)(ws + 196198400);
  u16* ztbuf = (u16*)ws;

  prep_weights<<<dim3(336), dim3(256), 0, stream>>>(wK, wQ, wV, wpK, wpQ, wpV);
  prep_x<<<dim3(16 * 256), dim3(256), 0, stream>>>(x, xbuf);
  conv_kq_mfma<<<dim3(16 * 256), dim3(256), 0, stream>>>(xbuf, wpK, wpQ, bK, bQ, qbuf, kbuf);
  scores_mfma<<<dim3(256), dim3(256), 0, stream>>>(qbuf, kbuf, pbuf);
  pv_mfma<<<dim3(1024), dim3(256), 0, stream>>>(pbuf, x, zraw);
  prep_z<<<dim3(16 * 256), dim3(256), 0, stream>>>(zraw, ztbuf);
  conv_out_mfma<<<dim3(16 * 256), dim3(256), 0, stream>>>(ztbuf, wpV, bV, out);
}

// Round 9
// 346.172 us; speedup vs baseline: 1.1413x; 1.1413x over previous
//
#include <hip/hip_runtime.h>
#include <hip/hip_bf16.h>

using uint32 = unsigned int;
using u16 = unsigned short;
using short8 = __attribute__((ext_vector_type(8))) short;
using f32x4  = __attribute__((ext_vector_type(4))) float;

// ---------- bf16 helpers ----------
__device__ __forceinline__ float bf2f(u16 u) {
  union { uint32 i; float f; } c; c.i = ((uint32)u) << 16; return c.f;
}
__device__ __forceinline__ u16 f2bf(float f) {
  union { float f; uint32 i; } c; c.f = f;
  uint32 u = c.i;
  u += 0x7fffu + ((u >> 16) & 1u);   // RNE
  return (u16)(u >> 16);
}
__device__ __forceinline__ uint32 pack2(float a, float b) {
  return (uint32)f2bf(a) | ((uint32)f2bf(b) << 16);
}

// async global->LDS, 16B per lane. LDS dest: wave-uniform base (+lane*16 by HW);
// global src: per-lane address.
__device__ __forceinline__ void gload_lds16(const void* g, void* l) {
  __builtin_amdgcn_global_load_lds(
      (const __attribute__((address_space(1))) unsigned int*)g,
      (__attribute__((address_space(3))) unsigned int*)l, 16, 0, 0);
}

// Sizes: B=16, C=64, W=256, H=128, H'=122, KW=7
// k/q layout: [b][co][w][h'] contiguous == (B,256,7808) attention rows
// raw flatten: row j=(c=j>>2, wblk=j&3); col e=(dw=e>>7, h=e&127)
// x/z tiles: per (b,w) [128 h][64 ci^((h&7)<<3)] bf16, 16384B

// ---------------------------------------------------------------
// Kernel 0: prep weights -> bf16 [kw][co][ci]
// ---------------------------------------------------------------
__global__ __launch_bounds__(256) void prep_weights(
    const float* __restrict__ wK, const float* __restrict__ wQ,
    const float* __restrict__ wV,
    u16* __restrict__ pK, u16* __restrict__ pQ, u16* __restrict__ pV)
{
  int idx = blockIdx.x * 256 + threadIdx.x;   // 0..86015
  if (idx >= 86016) return;
  int set = idx / 28672;
  int r = idx - set * 28672;                  // kw*4096 + co*64 + ci
  int kw = r >> 12;
  int rem = r & 4095;
  int co = rem >> 6, ci = rem & 63;
  const float* src = set == 0 ? wK : (set == 1 ? wQ : wV);
  u16* dst = set == 0 ? pK : (set == 1 ? pQ : pV);
  dst[r] = f2bf(src[co * 448 + ci * 7 + kw]);
}

// ---------------------------------------------------------------
// Kernel 0b: x -> swizzled bf16 tiles (streaming, full occupancy)
// ---------------------------------------------------------------
__global__ __launch_bounds__(256) void prep_x(
    const float* __restrict__ x, u16* __restrict__ xbuf)
{
  __shared__ u16 xt[128 * 64];
  const int bid = blockIdx.x;         // b*256 + w
  const int b = bid >> 8, w = bid & 255;
  const int t = threadIdx.x;
  const float* xb = x + (size_t)b * 2097152 + (size_t)w * 128;
  #pragma unroll
  for (int it = 0; it < 8; ++it) {
    int idx = t + it * 256;
    int h = idx & 127, gq = idx >> 7;
    int ci0 = gq * 4;
    float v0 = xb[(size_t)(ci0 + 0) * 32768 + h];
    float v1 = xb[(size_t)(ci0 + 1) * 32768 + h];
    float v2 = xb[(size_t)(ci0 + 2) * 32768 + h];
    float v3 = xb[(size_t)(ci0 + 3) * 32768 + h];
    uint2 pk; pk.x = pack2(v0, v1); pk.y = pack2(v2, v3);
    int col = ci0 ^ ((h & 7) << 3);
    *reinterpret_cast<uint2*>(&xt[h * 64 + col]) = pk;
  }
  __syncthreads();
  const uint4* s = reinterpret_cast<const uint4*>(xt);
  uint4* d = reinterpret_cast<uint4*>(xbuf + (size_t)bid * 8192);
  #pragma unroll
  for (int it = 0; it < 4; ++it) d[t + it * 256] = s[t + it * 256];
}

// ---------------------------------------------------------------
// Kernel 1: K and Q convs via MFMA. Staging = global_load_lds of the
// pre-swizzled tile. K-loop = pure LDS + MFMA (weights from L2 global).
// Epilogue: LDS transpose -> coalesced u32 row stores (244B rows).
// ---------------------------------------------------------------
__global__ __launch_bounds__(256, 4) void conv_kq_mfma(
    const u16* __restrict__ xbuf,
    const u16* __restrict__ wpK, const u16* __restrict__ wpQ,
    const float* __restrict__ bK, const float* __restrict__ bQ,
    u16* __restrict__ qbuf, u16* __restrict__ kbuf)
{
  __shared__ u16 xt[136 * 64];   // staging tile; reused as zs[64 co][136 n]
  const int bid = blockIdx.x;
  const int b = bid >> 8, w = bid & 255;
  const int t = threadIdx.x;
  const int lane = t & 63, wv = t >> 6;
  const int ln = lane & 15, g = lane >> 4;

  {
    const u16* src = xbuf + (size_t)bid * 8192;
    #pragma unroll
    for (int c = 0; c < 4; ++c) {
      int chunk = wv * 4 + c;                       // 16 chunks x 1024B
      gload_lds16(src + chunk * 512 + lane * 8, &xt[chunk * 512]);
    }
    if (t < 128) {   // zero pad rows 128..135
      *reinterpret_cast<uint2*>(&xt[128 * 64 + t * 4]) = make_uint2(0u, 0u);
    }
  }
  asm volatile("s_waitcnt vmcnt(0)" ::: "memory");
  __syncthreads();

  f32x4 accK[8], accQ[8];
  #pragma unroll
  for (int j = 0; j < 8; ++j) { accK[j] = (f32x4)0.f; accQ[j] = (f32x4)0.f; }

  for (int kw = 0; kw < 7; ++kw) {
    #pragma unroll
    for (int ks = 0; ks < 2; ++ks) {
      const int kb = ks * 32 + g * 8;
      const size_t woff = (size_t)(kw * 64 + wv * 16 + ln) * 64 + kb;
      short8 aK = *reinterpret_cast<const short8*>(wpK + woff);
      short8 aQ = *reinterpret_cast<const short8*>(wpQ + woff);
      #pragma unroll
      for (int j = 0; j < 8; ++j) {
        int row = j * 16 + ln + kw;
        int col = kb ^ ((row & 7) << 3);
        short8 bf = *reinterpret_cast<const short8*>(&xt[row * 64 + col]);
        accK[j] = __builtin_amdgcn_mfma_f32_16x16x32_bf16(aK, bf, accK[j], 0, 0, 0);
        accQ[j] = __builtin_amdgcn_mfma_f32_16x16x32_bf16(aQ, bf, accQ[j], 0, 0, 0);
      }
    }
  }
  __syncthreads();   // xt dead -> reuse as zs

  u16* zs = xt;      // [64 co][136 n] u16
  #pragma unroll
  for (int p = 0; p < 2; ++p) {
    // transpose-in: D col = ln -> n, row = g*4+r -> co
    #pragma unroll
    for (int r = 0; r < 4; ++r) {
      int co = wv * 16 + g * 4 + r;
      float bias = p ? bQ[co] : bK[co];
      #pragma unroll
      for (int j = 0; j < 8; ++j) {
        int n = j * 16 + ln;
        if (n < 122)
          zs[co * 136 + n] = f2bf((p ? accQ[j][r] : accK[j][r]) + bias);
      }
    }
    __syncthreads();
    // copy-out: 64 rows x 61 u32 (244B contiguous per (co,w) row)
    const uint32* zw = reinterpret_cast<const uint32*>(zs);
    uint32* dst = reinterpret_cast<uint32*>(p ? qbuf : kbuf);
    #pragma unroll
    for (int pass = 0; pass < 16; ++pass) {
      int idx = t + pass * 256;        // 0..4095
      int co = idx >> 6, u = idx & 63;
      if (u < 61)
        dst[((size_t)(b * 64 + co) * 256 + w) * 61 + u] = zw[co * 68 + u];
    }
    __syncthreads();
  }
}

// ---------------------------------------------------------------
// Kernel 2a: scores via MFMA + fused masked softmax -> pbuf bf16
// ---------------------------------------------------------------
__global__ __launch_bounds__(256) void scores_mfma(
    const u16* __restrict__ qbuf, const u16* __restrict__ kbuf,
    u16* __restrict__ pbuf)
{
  __shared__ float lmax[4][16];
  __shared__ float lsum[4][16];
  const int bid = blockIdx.x;
  const int b = bid & 15, rt = bid >> 4;
  const int t = threadIdx.x;
  const int lane = t & 63, wq = t >> 6;
  const int g = lane >> 4, ln = lane & 15;
  const int i0 = rt * 16;
  const int jbase = (rt < 8) ? 128 : 0;

  const u16* qp  = qbuf + (size_t)(b * 256 + i0 + ln) * 7808 + g * 8;
  const u16* kp0 = kbuf + (size_t)(b * 256 + jbase + wq * 32 + ln) * 7808 + g * 8;
  const u16* kp1 = kp0 + (size_t)16 * 7808;

  f32x4 acc0 = (f32x4)0.f, acc1 = (f32x4)0.f;
  #pragma unroll 4
  for (int c = 0; c < 244; ++c) {
    short8 af = *reinterpret_cast<const short8*>(qp + c * 32);
    short8 b0 = *reinterpret_cast<const short8*>(kp0 + c * 32);
    short8 b1 = *reinterpret_cast<const short8*>(kp1 + c * 32);
    acc0 = __builtin_amdgcn_mfma_f32_16x16x32_bf16(af, b0, acc0, 0, 0, 0);
    acc1 = __builtin_amdgcn_mfma_f32_16x16x32_bf16(af, b1, acc1, 0, 0, 0);
  }

  const float scale = 0.011316967f;    // 1/sqrt(7808)
  float s0[4], s1[4];
  #pragma unroll
  for (int r = 0; r < 4; ++r) { s0[r] = acc0[r] * scale; s1[r] = acc1[r] * scale; }

  float pm[4], ps[4];
  #pragma unroll
  for (int r = 0; r < 4; ++r) {
    float m = fmaxf(s0[r], s1[r]);
    #pragma unroll
    for (int off = 8; off >= 1; off >>= 1) m = fmaxf(m, __shfl_xor(m, off));
    float e = __expf(s0[r] - m) + __expf(s1[r] - m);
    #pragma unroll
    for (int off = 8; off >= 1; off >>= 1) e += __shfl_xor(e, off);
    pm[r] = m; ps[r] = e;
  }
  if (ln == 0) {
    #pragma unroll
    for (int r = 0; r < 4; ++r) {
      lmax[wq][g * 4 + r] = pm[r];
      lsum[wq][g * 4 + r] = ps[r];
    }
  }
  __syncthreads();

  #pragma unroll
  for (int r = 0; r < 4; ++r) {
    int row = g * 4 + r;
    float m0 = lmax[0][row], m1 = lmax[1][row], m2 = lmax[2][row], m3 = lmax[3][row];
    float mm = fmaxf(fmaxf(m0, m1), fmaxf(m2, m3));
    float ss = lsum[0][row] * __expf(m0 - mm) + lsum[1][row] * __expf(m1 - mm)
             + lsum[2][row] * __expf(m2 - mm) + lsum[3][row] * __expf(m3 - mm);
    float inv = 1.0f / ss;
    float p0 = __expf(s0[r] - mm) * inv;
    float p1 = __expf(s1[r] - mm) * inv;
    u16* prow = pbuf + (size_t)(b * 256 + i0 + row) * 128 + wq * 32 + ln;
    prow[0]  = f2bf(p0);
    prow[16] = f2bf(p1);
  }
}

// ---------------------------------------------------------------
// Kernel 2b: z = x + P*V via MFMA -> swizzled z TILES directly.
// acc[mt][nt][r]: tile w_img = r*64 + ec*2 + (nt>>3), h = (nt&7)*16+ln,
// chan c' = wv*8+mt*4+g (+cbase). Per-tile LDS transpose zs[h][c'] (stride
// 40 -> aligned uint4), copy-out applies the tile XOR swizzle.
// ---------------------------------------------------------------
__global__ __launch_bounds__(256) void pv_mfma(
    const u16* __restrict__ pbuf, const float* __restrict__ x,
    u16* __restrict__ ztbuf)
{
  __shared__ u16 smem[27648];          // pl[128*136] + vt[256*40]; zs overlays
  u16* pl = smem;
  u16* vt = smem + 17408;
  const int bid = blockIdx.x;
  const int b  = bid >> 6;
  const int hb = (bid >> 5) & 1;
  const int ec = bid & 31;
  const int t = threadIdx.x;
  const int lane = t & 63, wv = t >> 6;
  const int ln = lane & 15, g = lane >> 4;

  const int i0 = hb ? 0 : 128;        // output rows
  const int jbase = hb ? 128 : 0;     // V rows (opposite half)
  const int e0 = ec * 256;
  const float* xb = x + (size_t)b * 2097152;

  // stage P (bf16 rows, pad stride 136)
  {
    const u16* pb = pbuf + (size_t)(b * 256 + i0) * 128;
    #pragma unroll
    for (int it = 0; it < 8; ++it) {
      int idx = t + it * 256;           // 0..2047 uint4
      int row = idx >> 4, c = idx & 15;
      uint4 v = *reinterpret_cast<const uint4*>(pb + row * 128 + c * 8);
      *reinterpret_cast<uint4*>(&pl[row * 136 + c * 8]) = v;
    }
  }

  f32x4 acc[2][16];
  #pragma unroll
  for (int mt = 0; mt < 2; ++mt)
    #pragma unroll
    for (int nt = 0; nt < 16; ++nt) acc[mt][nt] = (f32x4)0.f;

  uint32* vtw = reinterpret_cast<uint32*>(vt);
  for (int ks = 0; ks < 4; ++ks) {
    __syncthreads();
    // stage V^T k-step: raw V rows jbase+ks*32..+32, cols e0..e0+256
    #pragma unroll
    for (int it = 0; it < 16; ++it) {
      int idx = t + it * 256;           // 0..4095
      int e = idx & 255, jp = idx >> 8;
      const float* vr = xb + (size_t)(jbase + ks * 32 + jp * 2) * 8192 + e0 + e;
      float f0 = vr[0];
      float f1 = vr[8192];
      vtw[e * 20 + jp] = pack2(f0, f1);
    }
    __syncthreads();
    short8 af[2];
    #pragma unroll
    for (int mt = 0; mt < 2; ++mt) {
      int row = wv * 32 + mt * 16 + ln;
      af[mt] = *reinterpret_cast<const short8*>(&pl[row * 136 + ks * 32 + g * 8]);
    }
    #pragma unroll
    for (int nt = 0; nt < 16; ++nt) {
      int e = nt * 16 + ln;
      short8 bf = *reinterpret_cast<const short8*>(&vt[e * 40 + g * 8]);
      acc[0][nt] = __builtin_amdgcn_mfma_f32_16x16x32_bf16(af[0], bf, acc[0][nt], 0, 0, 0);
      acc[1][nt] = __builtin_amdgcn_mfma_f32_16x16x32_bf16(af[1], bf, acc[1][nt], 0, 0, 0);
    }
  }

  // epilogue: per-tile transpose + swizzled copy-out
  u16* zs = smem;                      // [128 h][40] u16 (stride 40 -> 16B mult)
  const int cb5 = hb ? 0 : 1;          // cbase>>5
  const int cp_base = wv * 8 + g;
  for (int r = 0; r < 4; ++r) {
    for (int dwh = 0; dwh < 2; ++dwh) {
      __syncthreads();
      #pragma unroll
      for (int mt = 0; mt < 2; ++mt) {
        int i = i0 + wv * 32 + mt * 16 + g * 4 + r;
        int cp = cp_base + mt * 4;
        const float* xr = xb + (size_t)i * 8192 + e0 + dwh * 128 + ln;
        #pragma unroll
        for (int q = 0; q < 8; ++q) {
          float z = xr[q * 16] + acc[mt][dwh * 8 + q][r];
          zs[(q * 16 + ln) * 40 + cp] = f2bf(z);
        }
      }
      __syncthreads();
      int wimg = r * 64 + ec * 2 + dwh;
      u16* tb = ztbuf + (size_t)(b * 256 + wimg) * 8192;
      #pragma unroll
      for (int pass = 0; pass < 2; ++pass) {
        int idx = t + pass * 256;      // 0..511
        int h = idx >> 2, ch = idx & 3;
        uint4 v = *reinterpret_cast<const uint4*>(&zs[h * 40 + ch * 8]);
        int blk = 32 * (cb5 ^ ((h >> 2) & 1));
        int chd = ch ^ (h & 3);
        *reinterpret_cast<uint4*>(&tb[h * 64 + blk + chd * 8]) = v;
      }
    }
  }
}

// ---------------------------------------------------------------
// Kernel 3: y = LeakyReLU(conv(z, wV) + bV) via MFMA, fp32 out.
// Staging via global_load_lds from z tiles; epilogue LDS transpose
// -> coalesced uint2 row stores (488B rows, 8B-aligned).
// ---------------------------------------------------------------
__global__ __launch_bounds__(256, 4) void conv_out_mfma(
    const u16* __restrict__ ztbuf, const u16* __restrict__ wpV,
    const float* __restrict__ bV, float* __restrict__ out)
{
  __shared__ uint32 smem4[8448];       // 33792B: xt (17408) then zs_f32 (33792)
  u16* xt = reinterpret_cast<u16*>(smem4);
  const int bid = blockIdx.x;
  const int b = bid >> 8, w = bid & 255;
  const int t = threadIdx.x;
  const int lane = t & 63, wv = t >> 6;
  const int ln = lane & 15, g = lane >> 4;

  {
    const u16* src = ztbuf + (size_t)bid * 8192;
    #pragma unroll
    for (int c = 0; c < 4; ++c) {
      int chunk = wv * 4 + c;
      gload_lds16(src + chunk * 512 + lane * 8, &xt[chunk * 512]);
    }
    if (t < 128) {
      *reinterpret_cast<uint2*>(&xt[128 * 64 + t * 4]) = make_uint2(0u, 0u);
    }
  }
  asm volatile("s_waitcnt vmcnt(0)" ::: "memory");
  __syncthreads();

  f32x4 acc[8];
  #pragma unroll
  for (int j = 0; j < 8; ++j) acc[j] = (f32x4)0.f;

  for (int kw = 0; kw < 7; ++kw) {
    #pragma unroll
    for (int ks = 0; ks < 2; ++ks) {
      const int kb = ks * 32 + g * 8;
      const size_t woff = (size_t)(kw * 64 + wv * 16 + ln) * 64 + kb;
      short8 aV = *reinterpret_cast<const short8*>(wpV + woff);
      #pragma unroll
      for (int j = 0; j < 8; ++j) {
        int row = j * 16 + ln + kw;
        int col = kb ^ ((row & 7) << 3);
        short8 bf = *reinterpret_cast<const short8*>(&xt[row * 64 + col]);
        acc[j] = __builtin_amdgcn_mfma_f32_16x16x32_bf16(aV, bf, acc[j], 0, 0, 0);
      }
    }
  }
  __syncthreads();   // xt dead -> zs

  float* zsf = reinterpret_cast<float*>(smem4);   // [64 co][132 n] f32
  #pragma unroll
  for (int r = 0; r < 4; ++r) {
    int co = wv * 16 + g * 4 + r;
    float bv = bV[co];
    #pragma unroll
    for (int j = 0; j < 8; ++j) {
      int n = j * 16 + ln;
      if (n < 122) {
        float y = acc[j][r] + bv;
        zsf[co * 132 + n] = (y >= 0.f) ? y : 0.2f * y;
      }
    }
  }
  __syncthreads();
  // copy-out: 64 rows x 61 uint2 (488B contiguous per (co,w) row)
  const uint2* zw = reinterpret_cast<const uint2*>(zsf);
  #pragma unroll
  for (int pass = 0; pass < 16; ++pass) {
    int idx = t + pass * 256;          // 0..4095
    int co = idx >> 6, u = idx & 63;
    if (u < 61) {
      uint2* dst = reinterpret_cast<uint2*>(
          out + ((size_t)(b * 64 + co) * 256 + w) * 122);
      dst[u] = zw[co * 66 + u];
    }
  }
}

// ---------------------------------------------------------------
extern "C" void kernel_launch(void* const* d_in, const int* in_sizes, int n_in,
                              void* d_out, int out_size, void* d_ws, size_t ws_size,
                              hipStream_t stream) {
  const float* x  = (const float*)d_in[0];
  const float* wK = (const float*)d_in[1];
  const float* bK = (const float*)d_in[2];
  const float* wQ = (const float*)d_in[3];
  const float* bQ = (const float*)d_in[4];
  const float* wV = (const float*)d_in[5];
  const float* bV = (const float*)d_in[6];
  float* out = (float*)d_out;

  // workspace layout (196,255,744 B total):
  // [0)            qbuf bf16        63,963,136   dead after scores
  // [63,963,136)   kbuf bf16        63,963,136   dead after scores
  // [127,926,272)  pbuf bf16         1,048,576   live scores->pv
  // [128,974,848)  wpK/wpQ/wpV          172,032  (wpV live to conv_out)
  // [129,146,880)  xbuf -> ztbuf    67,108,864   (xbuf dead after conv_kq;
  //                                              pv writes ztbuf there)
  char* ws = (char*)d_ws;
  u16* qbuf  = (u16*)ws;
  u16* kbuf  = (u16*)(ws + 63963136);
  u16* pbuf  = (u16*)(ws + 127926272);
  u16* wpK   = (u16*)(ws + 128974848);
  u16* wpQ   = (u16*)(ws + 129032192);
  u16* wpV   = (u16*)(ws + 129089536);
  u16* xbuf  = (u16*)(ws + 129146880);
  u16* ztbuf = xbuf;

  prep_weights<<<dim3(336), dim3(256), 0, stream>>>(wK, wQ, wV, wpK, wpQ, wpV);
  prep_x<<<dim3(16 * 256), dim3(256), 0, stream>>>(x, xbuf);
  conv_kq_mfma<<<dim3(16 * 256), dim3(256), 0, stream>>>(xbuf, wpK, wpQ, bK, bQ, qbuf, kbuf);
  scores_mfma<<<dim3(256), dim3(256), 0, stream>>>(qbuf, kbuf, pbuf);
  pv_mfma<<<dim3(1024), dim3(256), 0, stream>>>(pbuf, x, ztbuf);
  conv_out_mfma<<<dim3(16 * 256), dim3(256), 0, stream>>>(ztbuf, wpV, bV, out);
}